// Round 14
// baseline (322.915 us; speedup 1.0000x reference)
//
#include <hip/hip_runtime.h>
#include <stdint.h>

typedef unsigned short u16;
typedef uint32_t u32;
typedef short s16x8 __attribute__((ext_vector_type(8)));
typedef float fx16 __attribute__((ext_vector_type(16)));

#define B_   256
#define H_   1024
#define BH_  (B_ * H_)                  // 262144
#define WPE  ((size_t)2 * 4096 * 2048)  // W pack elems
#define XPE  ((size_t)15 * BH_)
#define HPE  ((size_t)32 * BH_)
#define NT   32                         // K-steps (BK=64)

__device__ __forceinline__ u16 bf16_rn(float x) {
    union { float f; u32 u; } v; v.f = x;
    return (u16)((v.u + 0x7FFFu + ((v.u >> 16) & 1u)) >> 16);
}
__device__ __forceinline__ float sigf(float x) {
    return __builtin_amdgcn_rcpf(1.0f + __expf(-x));
}
__device__ __forceinline__ float tanh_f(float x) {
    return 1.0f - 2.0f * __builtin_amdgcn_rcpf(1.0f + __expf(2.0f * x));
}

// ---------------------------------------------------------------------------
__global__ __launch_bounds__(256)
void pack_weights(const float* __restrict__ Wih, const float* __restrict__ Whh,
                  u16* __restrict__ wp)
{
    const int gt = blockIdx.x * 256 + threadIdx.x;
    const int w = gt >> 6, lane = gt & 63;
    const int k16 = w & 127, cg = (w >> 7) & 31, gate = (w >> 12) & 3, layer = w >> 14;
    const int row = gate * 1024 + cg * 32 + (lane & 31);
    const int k = k16 * 16 + (lane >> 5) * 8;
    const float* src = (k < 1024)
        ? Wih + ((size_t)layer * 4096 + row) * 1024 + k
        : Whh + ((size_t)layer * 4096 + row) * 1024 + (k - 1024);
    const float4 v0 = *(const float4*)src;
    const float4 v1 = *(const float4*)(src + 4);
    const float a[8] = {v0.x, v0.y, v0.z, v0.w, v1.x, v1.y, v1.z, v1.w};
    union { u16 s[8]; uint4 v; } hi;
    #pragma unroll
    for (int e = 0; e < 8; ++e) hi.s[e] = bf16_rn(a[e]);
    *(uint4*)(wp + (size_t)w * 512 + (size_t)lane * 8) = hi.v;
}

__global__ __launch_bounds__(256)
void pack_x(const float* __restrict__ input, const float* __restrict__ bridge,
            u16* __restrict__ xp)
{
    const int gt = blockIdx.x * 256 + threadIdx.x;
    const int w = gt >> 6, lane = gt & 63;
    const int k16 = w & 63, btile = (w >> 6) & 7, n1 = w >> 9;
    const int b = btile * 32 + (lane & 31);
    const int k = k16 * 16 + (lane >> 5) * 8;
    const float* src = (k < 512)
        ? input  + ((size_t)n1 * 256 + b) * 512 + k
        : bridge + ((size_t)n1 * 256 + b) * 512 + (k - 512);
    const float4 v0 = *(const float4*)src;
    const float4 v1 = *(const float4*)(src + 4);
    const float a[8] = {v0.x, v0.y, v0.z, v0.w, v1.x, v1.y, v1.z, v1.w};
    union { u16 s[8]; uint4 v; } hi;
    #pragma unroll
    for (int e = 0; e < 8; ++e) hi.s[e] = bf16_rn(a[e]);
    *(uint4*)(xp + (size_t)w * 512 + (size_t)lane * 8) = hi.v;
}

__global__ __launch_bounds__(256)
void bias_sum_k(const float* __restrict__ bih, const float* __restrict__ bhh,
                float* __restrict__ bs)
{
    const int i = blockIdx.x * 256 + threadIdx.x;
    if (i < 8192) bs[i] = bih[i] + bhh[i];
}

// ---------------------------------------------------------------------------
// Whole-tree dataflow kernel, r8 body (128x128 tile, 32 KB LDS, BK=64).
// 30 cells (topo order, l0-first per level) x 64 blocks = 1920 blocks.
// 4 blocks/CU resident window (~16 cells lookahead); l0 seg0 (x @ W) is
// dependency-free fill work. Waits: l1 @ t=0 on own l0; seg1 @ t=16 on
// parent cell (skipped if par==0, which also halves those cells' K-loop).
// Flags: one u32 per cell in a PRIVATE 128-B slot; poll RELAXED/agent +
// s_sleep, single ACQUIRE on exit (no per-poll L1 invalidate — r9's bug).
// Publish: __syncthreads (per-wave vmcnt drain) + RELEASE/agent atomicAdd.
// ---------------------------------------------------------------------------
__constant__ signed char T_NODE[30] = {1,2,5,8,1,3,6,9,12,2,5,8,4,7,10,13,
                                       3,6,9,12,11,14,4,7,10,13,15,11,14,15};
__constant__ signed char T_PAR[30]  = {0,1,1,1,0,2,5,8,8,1,1,1,3,6,9,12,
                                       2,5,8,8,10,13,3,6,9,12,14,10,13,14};
__constant__ signed char T_LAY[30]  = {0,0,0,0,1,0,0,0,0,1,1,1,0,0,0,0,
                                       1,1,1,1,0,0,1,1,1,1,0,1,1,1};
__constant__ signed char T_D0[30]   = {-1,-1,-1,-1,0,-1,-1,-1,-1,1,2,3,-1,-1,-1,-1,
                                       5,6,7,8,-1,-1,12,13,14,15,-1,20,21,26};
__constant__ signed char T_D1[30]   = {-1,0,0,0,-1,1,2,3,3,4,4,4,5,6,7,8,
                                       9,10,11,11,14,15,16,17,18,19,21,24,25,28};

__device__ __forceinline__ void wait_cell(const u32* dcnt, int cidx) {
    if (threadIdx.x == 0) {
        const u32* p = dcnt + cidx * 32;
        while (__hip_atomic_load(p, __ATOMIC_RELAXED,
                                 __HIP_MEMORY_SCOPE_AGENT) < 64u) {
            __builtin_amdgcn_s_sleep(32);
        }
        (void)__hip_atomic_load(p, __ATOMIC_ACQUIRE, __HIP_MEMORY_SCOPE_AGENT);
    }
    __syncthreads();
}

__global__ __launch_bounds__(256, 4)
void cell_tree(const u16* __restrict__ wp, const u16* __restrict__ xp,
               u16* __restrict__ hp, float* __restrict__ c_buf,
               const float* __restrict__ bsum, float* __restrict__ out,
               u32* __restrict__ dcnt)
{
    __shared__ __align__(16) char SMEM[37376];
    u16*   AL   = (u16*)SMEM;            // [btl(4)][kk(4)][512] = 16 KB
    u16*   WL   = AL + 8192;             // [g(4)][kk(4)][512]   = 16 KB
    float* gbuf = (float*)SMEM;          // [64][129] f32 (epilogue overlay)
    u16*   tbuf = (u16*)(SMEM + 33024);  // [64][33] u16 (epilogue overlay)

    const int bid  = blockIdx.x;
    const int cidx = bid >> 6;
    const int u    = bid & 63;
    const int hhblk = 4 * (u & 7) + ((u >> 3) & 3);   // 0..31, XCD-stable
    const int mblk  = u >> 5;                          // 0..1
    const int node = T_NODE[cidx], par = T_PAR[cidx], layer = T_LAY[cidx];
    const int d0 = T_D0[cidx], d1 = T_D1[cidx];
    const int tid = threadIdx.x, wv = tid >> 6, lane = tid & 63;
    const int mw = wv >> 1, nw = wv & 1;
    const int tg = tid >> 6;
    const int tl8 = (tid & 63) * 8;

    // A segment bases (seg0 = K 0..1023, seg1 = K 1024..2047)
    const u16 *A0, *A1;
    if (layer == 0) {
        A0 = xp + (size_t)(node - 1) * BH_;
        A1 = hp + (size_t)(par * 2 + 0) * BH_;
    } else {
        A0 = hp + (size_t)(node * 2 + 0) * BH_;
        A1 = hp + (size_t)(par * 2 + 1) * BH_;
    }
    size_t wsrc[4];
    #pragma unroll
    for (int g = 0; g < 4; ++g)
        wsrc[g] = ((size_t)((layer * 4 + g) * 32 + hhblk) * 128 + tg) * 512
                + (size_t)tl8;

    // par==0 -> parent h/c are zeros: skip seg1 entirely (adds exact zeros)
    const int nsteps = (par == 0) ? (NT / 2) : NT;

    if (layer == 1) wait_cell(dcnt, d0);    // own l0 h before seg0

    fx16 acc[2][2];
    #pragma unroll
    for (int m = 0; m < 2; ++m)
        #pragma unroll
        for (int n = 0; n < 2; ++n)
            #pragma unroll
            for (int r = 0; r < 16; ++r) acc[m][n][r] = 0.0f;

    #pragma unroll 1
    for (int t = 0; t < nsteps; ++t) {
        if (t == 16 && d1 >= 0) wait_cell(dcnt, d1);   // parent h before seg1
        // ---- stage: A 16KB (btl=i, kq=tg) + W 16KB (g=i)
        const u16* As = (t < 16) ? A0 : A1;
        const int k16 = (t & 15) * 4 + tg;
        #pragma unroll
        for (int i = 0; i < 4; ++i) {
            __builtin_amdgcn_global_load_lds(
                (const __attribute__((address_space(1))) void*)
                    (As + ((size_t)(mblk * 4 + i) * 64 + k16) * 512 + tl8),
                (__attribute__((address_space(3))) void*)
                    (AL + (i * 4 + tg) * 512 + tl8),
                16, 0, 0);
        }
        #pragma unroll
        for (int i = 0; i < 4; ++i) {
            __builtin_amdgcn_global_load_lds(
                (const __attribute__((address_space(1))) void*)
                    (wp + wsrc[i] + (size_t)t * 4 * 512),
                (__attribute__((address_space(3))) void*)
                    (WL + (i * 4 + tg) * 512 + tl8),
                16, 0, 0);
        }
        __syncthreads();
        // ---- compute
        #pragma unroll
        for (int kk = 0; kk < 4; ++kk) {
            s16x8 a[2], w[2];
            #pragma unroll
            for (int m = 0; m < 2; ++m)
                a[m] = *(const s16x8*)(AL + ((mw * 2 + m) * 4 + kk) * 512 + lane * 8);
            #pragma unroll
            for (int n = 0; n < 2; ++n)
                w[n] = *(const s16x8*)(WL + ((nw * 2 + n) * 4 + kk) * 512 + lane * 8);
            #pragma unroll
            for (int m = 0; m < 2; ++m)
                #pragma unroll
                for (int n = 0; n < 2; ++n)
                    acc[m][n] = __builtin_amdgcn_mfma_f32_32x32x16_bf16(
                        a[m], w[n], acc[m][n], 0, 0, 0);
        }
        __syncthreads();
    }

    // ---- fused epilogue (C/D: col=lane&31, row=(r&3)+8*(r>>2)+4*(lane>>5))
    const int hhl  = tid & 31;
    const int colg = hhblk * 32 + hhl;
    float bs4[4];
    #pragma unroll
    for (int g = 0; g < 4; ++g)
        bs4[g] = bsum[layer * 4096 + g * 1024 + colg];

    const float* cpar = c_buf + (size_t)(par * 2 + layer) * BH_ + colg;
    float*       cnew = c_buf + (size_t)(node * 2 + layer) * BH_ + colg;
    float*       outp = out + (size_t)(node - 1) * BH_ + colg;
    u16*         hpn  = hp + (size_t)(node * 2 + layer) * BH_;

    #pragma unroll
    for (int p = 0; p < 2; ++p) {
        __syncthreads();
        if (mw == p) {
            #pragma unroll
            for (int m = 0; m < 2; ++m) {
                #pragma unroll
                for (int n = 0; n < 2; ++n) {
                    const int col = (nw * 2 + n) * 32 + (lane & 31);
                    #pragma unroll
                    for (int r = 0; r < 16; ++r) {
                        const int row_l = m * 32 + 4 * (lane >> 5)
                                        + (r & 3) + 8 * (r >> 2);
                        gbuf[row_l * 129 + col] = acc[m][n][r];
                    }
                }
            }
        }
        __syncthreads();
        #pragma unroll
        for (int e = 0; e < 8; ++e) {
            const int row_l = e * 8 + (tid >> 5);
            const size_t grow = (size_t)(mblk * 128 + p * 64 + row_l) * 1024;
            const float gi = gbuf[row_l * 129 + 0 * 32 + hhl] + bs4[0];
            const float gf = gbuf[row_l * 129 + 1 * 32 + hhl] + bs4[1];
            const float gg = gbuf[row_l * 129 + 2 * 32 + hhl] + bs4[2];
            const float go = gbuf[row_l * 129 + 3 * 32 + hhl] + bs4[3];
            const float cp = cpar[grow];
            const float cn = sigf(gf) * cp + sigf(gi) * tanh_f(gg);
            const float hn = sigf(go) * tanh_f(cn);
            cnew[grow] = cn;
            if (layer == 1) outp[grow] = hn;
            tbuf[row_l * 33 + hhl] = bf16_rn(hn);
        }
        __syncthreads();
        {
            const int j = wv >> 1, q = wv & 1;
            const int bt   = mblk * 4 + p * 2 + j;
            const int k16h = hhblk * 2 + q;
            union { u16 s[8]; uint4 v; } pk;
            #pragma unroll
            for (int e = 0; e < 8; ++e)
                pk.s[e] = tbuf[(j * 32 + (lane & 31)) * 33
                               + q * 16 + (lane >> 5) * 8 + e];
            *(uint4*)(hpn + ((size_t)bt * 64 + k16h) * 512 + lane * 8) = pk.v;
        }
    }

    // ---- publish: each wave drained its stores at the barrier; release flag
    __syncthreads();
    if (tid == 0)
        __hip_atomic_fetch_add(dcnt + cidx * 32, 1,
                               __ATOMIC_RELEASE, __HIP_MEMORY_SCOPE_AGENT);
}

// ---------------------------------------------------------------------------
extern "C" void kernel_launch(void* const* d_in, const int* in_sizes, int n_in,
                              void* d_out, int out_size, void* d_ws, size_t ws_size,
                              hipStream_t stream)
{
    const float* input  = (const float*)d_in[0];
    const float* bridge = (const float*)d_in[1];
    const float* Wih    = (const float*)d_in[2];
    const float* Whh    = (const float*)d_in[3];
    const float* bih    = (const float*)d_in[4];
    const float* bhh    = (const float*)d_in[5];
    float* out = (float*)d_out;

    u16* wp = (u16*)d_ws;
    u16* xp = wp + WPE;
    u16* hp = xp + XPE;
    float* c_buf = (float*)(hp + HPE);
    float* bsum  = c_buf + HPE;
    u32*   dcnt  = (u32*)(bsum + 8192);

    hipMemsetAsync(hp, 0, (size_t)2 * BH_ * sizeof(u16), stream);
    hipMemsetAsync(c_buf, 0, (size_t)2 * BH_ * sizeof(float), stream);
    hipMemsetAsync(dcnt, 0, 30 * 32 * sizeof(u32), stream);

    bias_sum_k<<<32, 256, 0, stream>>>(bih, bhh, bsum);
    pack_weights<<<8192, 256, 0, stream>>>(Wih, Whh, wp);
    pack_x<<<1920, 256, 0, stream>>>(input, bridge, xp);

    cell_tree<<<dim3(30 * 64), 256, 0, stream>>>(
        wp, xp, hp, c_buf, bsum, out, dcnt);
}